// Round 2
// baseline (677.020 us; speedup 1.0000x reference)
//
#include <hip/hip_runtime.h>
#include <hip/hip_bf16.h>
#include <math.h>

// ResidualCache: out = softmax(top4(cos_sim(q, keys))) @ values
// Pipeline: [nrm] fp32->bf16 normalized rows  [score] bf16 MFMA GEMM + per-lane top-4
//           [final] merge candidates -> fp32 exact rescore -> top-k -> softmax -> gather
// R1 fix: candidate buffer now indexed by wr (key-half) -> no cross-wave write race.

#define D_DIM 1024
#define SLICES 4
#define BQ 128
#define BK 128
#define BD 64
#define TLIST 4
#define CAND_PER_Q (SLICES * 2 * 4 * TLIST)   // 128

typedef float f32x4 __attribute__((ext_vector_type(4)));
typedef short s16x8 __attribute__((ext_vector_type(8)));

typedef const __attribute__((address_space(1))) void* as1cv;
typedef __attribute__((address_space(3))) void* as3v;

__device__ __forceinline__ void gload_lds16(const void* g, void* l) {
    __builtin_amdgcn_global_load_lds((as1cv)g, (as3v)l, 16, 0, 0);
}

// round-to-nearest-even fp32 -> bf16 bits
__device__ __forceinline__ unsigned short f2bf(float x) {
    unsigned int u;
    __builtin_memcpy(&u, &x, 4);
    unsigned int r = (u + 0x7fffu + ((u >> 16) & 1u)) >> 16;
    return (unsigned short)r;
}

// ---------------- kernel 1: L2-normalize rows, emit bf16 + inv-norm ----------------
__global__ __launch_bounds__(256) void nrm_kernel(
    const float* __restrict__ q, const float* __restrict__ kmat,
    unsigned short* __restrict__ qn, unsigned short* __restrict__ kn,
    float* __restrict__ inv_qn, float* __restrict__ inv_kn, int B, int N) {
    int wid = threadIdx.x >> 6, lane = threadIdx.x & 63;
    int row = blockIdx.x * 4 + wid;
    if (row >= B + N) return;
    const float* src;
    unsigned short* dst;
    float* invp;
    if (row < B) {
        src = q + (size_t)row * D_DIM; dst = qn + (size_t)row * D_DIM; invp = inv_qn + row;
    } else {
        int r = row - B;
        src = kmat + (size_t)r * D_DIM; dst = kn + (size_t)r * D_DIM; invp = inv_kn + r;
    }
    float4 v[4];
    float ss = 0.f;
#pragma unroll
    for (int c = 0; c < 4; ++c) {
        v[c] = *(const float4*)(src + c * 256 + lane * 4);
        ss += v[c].x * v[c].x + v[c].y * v[c].y + v[c].z * v[c].z + v[c].w * v[c].w;
    }
#pragma unroll
    for (int m = 1; m < 64; m <<= 1) ss += __shfl_xor(ss, m, 64);
    float s = 1.0f / fmaxf(sqrtf(ss), 1e-12f);
    if (lane == 0) *invp = s;
#pragma unroll
    for (int c = 0; c < 4; ++c) {
        ushort4 o;
        o.x = f2bf(v[c].x * s); o.y = f2bf(v[c].y * s);
        o.z = f2bf(v[c].z * s); o.w = f2bf(v[c].w * s);
        *(ushort4*)(dst + c * 256 + lane * 4) = o;
    }
}

// ---------------- kernel 2: bf16 MFMA sim GEMM + per-lane top-4 candidates ----------------
// Grid: (B/BQ)*SLICES blocks of 256. slice = blockIdx&3 (one slice per XCD L2).
// Wave (wr,wc) covers keys [wr*64,+64) x queries [wc*64,+64) of the 128x128 tile.
// C/D frag (16x16x32): col(query)=lane&15, row(key)=(lane>>4)*4+j  [m89-verified]
__global__ __launch_bounds__(256, 2) void score_kernel(
    const unsigned short* __restrict__ qn, const unsigned short* __restrict__ kn,
    float* __restrict__ cand_s, int* __restrict__ cand_i, int B, int N) {
    __shared__ __attribute__((aligned(16))) unsigned short Kt[BK * BD];
    __shared__ __attribute__((aligned(16))) unsigned short Qt[BQ * BD];
    int bx = blockIdx.x;
    int qblk = bx >> 2, slice = bx & 3;
    int tid = threadIdx.x, wid = tid >> 6, lane = tid & 63;
    int wr = wid & 1, wc = wid >> 1;
    int slice_len = N / SLICES;           // 2048
    int kbase0 = slice * slice_len;
    int qbase = qblk * BQ;

    float ts[4][TLIST];
    int   ti[4][TLIST];
#pragma unroll
    for (int cg = 0; cg < 4; ++cg)
#pragma unroll
        for (int t = 0; t < TLIST; ++t) { ts[cg][t] = -1e30f; ti[cg][t] = 0; }

    for (int kt = 0; kt < slice_len / BK; ++kt) {
        int kb = kbase0 + kt * BK;
        f32x4 acc[4][4];
#pragma unroll
        for (int a = 0; a < 4; ++a)
#pragma unroll
            for (int b = 0; b < 4; ++b) acc[a][b] = (f32x4){0.f, 0.f, 0.f, 0.f};

        for (int dc = 0; dc < D_DIM / BD; ++dc) {
            int db = dc * BD;
            // stage K tile (128x64 bf16) and Q tile (128x64) via global_load_lds w=16.
            // LDS dest linear; source col pre-swizzled: slot s of row r holds cols (s^(r&7))*8.
#pragma unroll
            for (int i = 0; i < 4; ++i) {
                int te = (i * 4 + wid) * 64 + lane;
                int r = te >> 3, sl = te & 7;
                int c = (sl ^ (r & 7)) * 8;
                gload_lds16(kn + (size_t)(kb + r) * D_DIM + db + c, &Kt[(i * 4 + wid) * 512]);
            }
#pragma unroll
            for (int i = 0; i < 4; ++i) {
                int te = (i * 4 + wid) * 64 + lane;
                int r = te >> 3, sl = te & 7;
                int c = (sl ^ (r & 7)) * 8;
                gload_lds16(qn + (size_t)(qbase + r) * D_DIM + db + c, &Qt[(i * 4 + wid) * 512]);
            }
            __syncthreads();
#pragma unroll
            for (int ks = 0; ks < 2; ++ks) {
                int kslot = ks * 4 + (lane >> 4);   // 16B slot index in row
                s16x8 afr[4], bfr[4];
#pragma unroll
                for (int rb = 0; rb < 4; ++rb) {
                    int row = wr * 64 + rb * 16 + (lane & 15);
                    afr[rb] = *(const s16x8*)&Kt[row * BD + ((kslot ^ (row & 7)) * 8)];
                }
#pragma unroll
                for (int cg = 0; cg < 4; ++cg) {
                    int row = wc * 64 + cg * 16 + (lane & 15);
                    bfr[cg] = *(const s16x8*)&Qt[row * BD + ((kslot ^ (row & 7)) * 8)];
                }
#pragma unroll
                for (int rb = 0; rb < 4; ++rb)
#pragma unroll
                    for (int cg = 0; cg < 4; ++cg)
                        acc[rb][cg] = __builtin_amdgcn_mfma_f32_16x16x32_bf16(
                            afr[rb], bfr[cg], acc[rb][cg], 0, 0, 0);
            }
            __syncthreads();
        }
        // top-4 update: lane holds, per query-colgroup cg, 16 sims (4 rb x 4 j)
#pragma unroll
        for (int rb = 0; rb < 4; ++rb) {
#pragma unroll
            for (int j = 0; j < 4; ++j) {
                int key = kb + wr * 64 + rb * 16 + ((lane >> 4) << 2) + j;
#pragma unroll
                for (int cg = 0; cg < 4; ++cg) {
                    float s = acc[rb][cg][j];
                    if (s > ts[cg][TLIST - 1]) {
                        int id = key;
#pragma unroll
                        for (int t = 0; t < TLIST; ++t) {   // bubble-insert, keeps desc order
                            bool c = s > ts[cg][t];
                            float hi = c ? s : ts[cg][t];
                            float lo = c ? ts[cg][t] : s;
                            int ih = c ? id : ti[cg][t];
                            int il = c ? ti[cg][t] : id;
                            ts[cg][t] = hi; ti[cg][t] = ih; s = lo; id = il;
                        }
                    }
                }
            }
        }
    }
    // write candidates: cand[q][slice][wr][lanegrp][TLIST]  (wr in address -> no race)
#pragma unroll
    for (int cg = 0; cg < 4; ++cg) {
        int qg = qbase + wc * 64 + cg * 16 + (lane & 15);
        int lg = lane >> 4;
        size_t base = (size_t)qg * CAND_PER_Q + slice * (2 * 4 * TLIST) + wr * (4 * TLIST) + lg * TLIST;
#pragma unroll
        for (int t = 0; t < TLIST; ++t) {
            cand_s[base + t] = ts[cg][t];
            cand_i[base + t] = ti[cg][t];
        }
    }
}

// ---------------- kernel 3: merge -> exact fp32 rescore -> top-k -> softmax -> gather ----------------
__global__ __launch_bounds__(256) void final_kernel(
    const float* __restrict__ q, const float* __restrict__ kmat, const float* __restrict__ vmat,
    const float* __restrict__ inv_qn, const float* __restrict__ inv_kn,
    const float* __restrict__ cand_s, const int* __restrict__ cand_i,
    const int* __restrict__ kptr, float* __restrict__ out, int B, int N) {
    int qi = blockIdx.x;
    int tid = threadIdx.x, lane = tid & 63, wid = tid >> 6;
    __shared__ int sel[8];
    __shared__ float exsc[8];
    __shared__ float wgt[8];
    __shared__ int widx[8];
    int kk = *kptr;
    kk = kk < 1 ? 1 : (kk > 8 ? 8 : kk);

    // phase 1: wave 0 extracts approx top-8 of the 128 candidates
    if (wid == 0) {
        size_t cb = (size_t)qi * CAND_PER_Q;
        float s0 = cand_s[cb + lane], s1 = cand_s[cb + 64 + lane];
        int i0 = cand_i[cb + lane], i1 = cand_i[cb + 64 + lane];
        if (s1 > s0) { float tf = s0; s0 = s1; s1 = tf; int tt = i0; i0 = i1; i1 = tt; }
        for (int it = 0; it < 8; ++it) {
            float v = s0; int ki = i0; int ln = lane;
#pragma unroll
            for (int m = 1; m < 64; m <<= 1) {
                float ov = __shfl_xor(v, m, 64);
                int oki = __shfl_xor(ki, m, 64);
                int oln = __shfl_xor(ln, m, 64);
                if (ov > v || (ov == v && oki < ki)) { v = ov; ki = oki; ln = oln; }
            }
            if (lane == ln) { s0 = s1; i0 = i1; s1 = -1e30f; }
            if (lane == 0) sel[it] = ki;
        }
    }
    __syncthreads();

    // phase 2: exact fp32 rescore of 8 candidates (32 threads each)
    int c = tid >> 5, l5 = tid & 31;
    const float* qrow = q + (size_t)qi * D_DIM;
    int kidx = sel[c];
    const float* krow = kmat + (size_t)kidx * D_DIM;
    float p = 0.f;
#pragma unroll
    for (int e = 0; e < 32; ++e) {
        int d = e * 32 + l5;
        p += qrow[d] * krow[d];
    }
#pragma unroll
    for (int m = 1; m < 32; m <<= 1) p += __shfl_xor(p, m, 64);
    if (l5 == 0) exsc[c] = p * inv_qn[qi] * inv_kn[kidx];
    __syncthreads();

    // phase 3: exact top-k (ties -> lower index, matches jax.lax.top_k) + softmax
    if (tid == 0) {
        float sc[8]; int id[8]; bool used[8];
#pragma unroll
        for (int i = 0; i < 8; ++i) { sc[i] = exsc[i]; id[i] = sel[i]; used[i] = false; }
        float wl[8]; int il[8];
        for (int i = 0; i < kk; ++i) {
            int bj = 0; float bv = -1e30f; int bi = 0x7fffffff;
            for (int j = 0; j < 8; ++j) {
                if (!used[j] && (sc[j] > bv || (sc[j] == bv && id[j] < bi))) {
                    bv = sc[j]; bi = id[j]; bj = j;
                }
            }
            used[bj] = true; wl[i] = bv; il[i] = bi;
        }
        float m0 = wl[0], ssum = 0.f;
        for (int i = 0; i < kk; ++i) { wl[i] = expf(wl[i] - m0); ssum += wl[i]; }
        for (int i = 0; i < kk; ++i) { wgt[i] = wl[i] / ssum; widx[i] = il[i]; }
    }
    __syncthreads();

    // phase 4: out = sum_i w_i * values[idx_i]
    int d0 = tid * 4;
    float4 o = {0.f, 0.f, 0.f, 0.f};
    for (int i = 0; i < kk; ++i) {
        const float4 vv = *(const float4*)(vmat + (size_t)widx[i] * D_DIM + d0);
        float wi = wgt[i];
        o.x += wi * vv.x; o.y += wi * vv.y; o.z += wi * vv.z; o.w += wi * vv.w;
    }
    *(float4*)(out + (size_t)qi * D_DIM + d0) = o;
}

extern "C" void kernel_launch(void* const* d_in, const int* in_sizes, int n_in,
                              void* d_out, int out_size, void* d_ws, size_t ws_size,
                              hipStream_t stream) {
    const float* q = (const float*)d_in[0];
    const float* kmat = (const float*)d_in[1];
    const float* vmat = (const float*)d_in[2];
    const int* kptr = (const int*)d_in[3];
    float* out = (float*)d_out;
    int B = in_sizes[0] / D_DIM;   // 16384
    int N = in_sizes[1] / D_DIM;   // 8192

    char* ws = (char*)d_ws;
    size_t off = 0;
    unsigned short* qn = (unsigned short*)(ws + off); off += (size_t)B * D_DIM * 2;
    unsigned short* kn = (unsigned short*)(ws + off); off += (size_t)N * D_DIM * 2;
    float* inv_qn = (float*)(ws + off); off += (size_t)B * 4;
    float* inv_kn = (float*)(ws + off); off += (size_t)N * 4;
    float* cand_s = (float*)(ws + off); off += (size_t)B * CAND_PER_Q * 4;
    int* cand_i = (int*)(ws + off); off += (size_t)B * CAND_PER_Q * 4;
    // total ~64.2 MB of d_ws

    int rows = B + N;
    nrm_kernel<<<dim3((rows + 3) / 4), dim3(256), 0, stream>>>(q, kmat, qn, kn, inv_qn, inv_kn, B, N);
    score_kernel<<<dim3((B / BQ) * SLICES), dim3(256), 0, stream>>>(qn, kn, cand_s, cand_i, B, N);
    final_kernel<<<dim3(B), dim3(256), 0, stream>>>(q, kmat, vmat, inv_qn, inv_kn,
                                                    cand_s, cand_i, kptr, out, B, N);
}